// Round 2
// baseline (48.122 us; speedup 1.0000x reference)
//
#include <hip/hip_runtime.h>
#include <math.h>

#define A_N 200000
#define B_N 8
#define M_N 32
#define THREADS 256
#define APT 4                       // anchors per thread
#define APB (THREADS * APT)         // anchors per block = 1024
#define BPI ((A_N + APB - 1) / APB) // blocks per image = 196

__device__ __forceinline__ float sl1(float d) {
    d = fabsf(d);
    return (d <= (1.0f / 9.0f)) ? (4.5f * d * d) : (d - (1.0f / 18.0f));
}

__global__ __launch_bounds__(THREADS)
void focal_main(const float* __restrict__ cls,
                const float4* __restrict__ reg,
                const float4* __restrict__ anchors,
                const float* __restrict__ ann,
                float* __restrict__ partials)
{
    const int blk = blockIdx.x;
    const int b   = blockIdx.y;
    const int tid = threadIdx.x;

    __shared__ float4 sbox[M_N];
    __shared__ float  sarea[M_N];
    __shared__ float  wred[THREADS / 64][3];

    if (tid < M_N) {
        const float* p = ann + (size_t)(b * M_N + tid) * 5;
        float x1 = p[0], y1 = p[1], x2 = p[2], y2 = p[3];
        sbox[tid]  = make_float4(x1, y1, x2, y2);
        sarea[tid] = (x2 - x1) * (y2 - y1);
    }
    __syncthreads();

    const int abase = blk * APB + tid;

    float ax1[APT], ay1[APT], ax2[APT], ay2[APT], areaA[APT];
    float bi[APT], bu[APT];   // best inter / best ua
    int   bj[APT];
    float pcls[APT];          // hoisted cls loads (latency hidden under j-loop)
    #pragma unroll
    for (int k = 0; k < APT; k++) {
        int a  = abase + k * THREADS;
        int al = (a < A_N) ? a : (A_N - 1);
        float4 v = anchors[al];
        ax1[k] = v.x; ay1[k] = v.y; ax2[k] = v.z; ay2[k] = v.w;
        areaA[k] = (v.z - v.x) * (v.w - v.y);
        bi[k] = -1.0f; bu[k] = 1.0f; bj[k] = 0;
        pcls[k] = cls[((size_t)b * A_N + al) * 4];   // channel 0 only contributes
    }

    #pragma unroll 4
    for (int j = 0; j < M_N; j++) {
        float4 bb = sbox[j];
        float  ab = sarea[j];
        #pragma unroll
        for (int k = 0; k < APT; k++) {
            float iw = fminf(ax2[k], bb.z) - fmaxf(ax1[k], bb.x);
            float ih = fminf(ay2[k], bb.w) - fmaxf(ay1[k], bb.y);
            iw = fmaxf(iw, 0.0f);
            ih = fmaxf(ih, 0.0f);
            float inter = iw * ih;
            float ua = areaA[k] + ab - inter;   // ua >= 64 always, clamp to 1e-8 never binds
            // iou_j > iou_best  <=>  inter_j * ua_best > inter_best * ua_j  (ua > 0)
            bool c = inter * bu[k] > bi[k] * ua;
            bi[k] = c ? inter : bi[k];
            bu[k] = c ? ua    : bu[k];
            bj[k] = c ? j     : bj[k];
        }
    }

    float cls_sum = 0.0f, reg_sum = 0.0f, npos = 0.0f;
    #pragma unroll
    for (int k = 0; k < APT; k++) {
        int a = abase + k * THREADS;
        if (a >= A_N) continue;
        float iou = bi[k] / bu[k];
        bool pos = iou >= 0.5f;
        bool neg = iou < 0.4f;
        float p = fminf(fmaxf(pcls[k], 1e-5f), 1.0f - 1e-5f);
        // single-log focal term: q = pos ? p : 1-p ; loss = coef * (1-q)^2 * (-log q)
        float q    = pos ? p : (1.0f - p);
        float coef = pos ? 0.25f : 0.75f;
        float omq  = 1.0f - q;
        float term = coef * omq * omq * (-__logf(q));
        cls_sum += (pos || neg) ? term : 0.0f;
        npos    += pos ? 1.0f : 0.0f;
        if (pos) {   // rare: exec-z skipped for most waves
            float4 bb = sbox[bj[k]];
            float aw = ax2[k] - ax1[k], ah = ay2[k] - ay1[k];
            float acx = ax1[k] + 0.5f * aw, acy = ay1[k] + 0.5f * ah;
            float gwr = bb.z - bb.x, ghr = bb.w - bb.y;
            float gcx = bb.x + 0.5f * gwr, gcy = bb.y + 0.5f * ghr;
            float gw = fmaxf(gwr, 1.0f), gh = fmaxf(ghr, 1.0f);
            float4 r = reg[(size_t)b * A_N + a];
            float rt0 = ((gcx - acx) / aw) / 0.1f;
            float rt1 = ((gcy - acy) / ah) / 0.1f;
            float rt2 = __logf(gw / aw) / 0.2f;
            float rt3 = __logf(gh / ah) / 0.2f;
            reg_sum += sl1(rt0 - r.x) + sl1(rt1 - r.y) + sl1(rt2 - r.z) + sl1(rt3 - r.w);
        }
    }

    // wave reduce (64 lanes)
    #pragma unroll
    for (int off = 32; off > 0; off >>= 1) {
        cls_sum += __shfl_down(cls_sum, off);
        reg_sum += __shfl_down(reg_sum, off);
        npos    += __shfl_down(npos, off);
    }
    int wid = tid >> 6;
    if ((tid & 63) == 0) {
        wred[wid][0] = cls_sum; wred[wid][1] = reg_sum; wred[wid][2] = npos;
    }
    __syncthreads();
    if (tid == 0) {
        float c = 0.0f, r = 0.0f, n = 0.0f;
        #pragma unroll
        for (int w = 0; w < THREADS / 64; w++) {
            c += wred[w][0]; r += wred[w][1]; n += wred[w][2];
        }
        float* dst = partials + (size_t)(b * BPI + blk) * 3;
        dst[0] = c; dst[1] = r; dst[2] = n;
    }
}

__global__ void focal_reduce(const float* __restrict__ partials, float* __restrict__ out)
{
    int tid = threadIdx.x;  // 64 threads, 1 wave
    float cacc = 0.0f, racc = 0.0f;
    for (int b = 0; b < B_N; b++) {
        float cs = 0.0f, rs = 0.0f, np = 0.0f;
        for (int i = tid; i < BPI; i += 64) {
            const float* p = partials + (size_t)(b * BPI + i) * 3;
            cs += p[0]; rs += p[1]; np += p[2];
        }
        #pragma unroll
        for (int off = 32; off > 0; off >>= 1) {
            cs += __shfl_down(cs, off);
            rs += __shfl_down(rs, off);
            np += __shfl_down(np, off);
        }
        if (tid == 0) {
            cacc += cs / fmaxf(np, 1.0f);
            racc += (np > 0.0f) ? (rs / (4.0f * np)) : 0.0f;
        }
    }
    if (tid == 0) {
        out[0] = cacc / (float)B_N;
        out[1] = racc / (float)B_N;
    }
}

extern "C" void kernel_launch(void* const* d_in, const int* in_sizes, int n_in,
                              void* d_out, int out_size, void* d_ws, size_t ws_size,
                              hipStream_t stream)
{
    const float*  cls     = (const float*)d_in[0];
    const float4* reg     = (const float4*)d_in[1];
    const float4* anchors = (const float4*)d_in[2];
    const float*  ann     = (const float*)d_in[3];
    float* partials = (float*)d_ws;   // [B_N][BPI][3] floats, every slot written each launch
    float* out      = (float*)d_out;

    dim3 grid(BPI, B_N);
    focal_main<<<grid, THREADS, 0, stream>>>(cls, reg, anchors, ann, partials);
    focal_reduce<<<1, 64, 0, stream>>>(partials, out);
}

// Round 3
// 36.064 us; speedup vs baseline: 1.3343x; 1.3343x over previous
//
#include <hip/hip_runtime.h>
#include <math.h>

#define A_N 200000
#define B_N 8
#define M_N 32
#define THREADS 256
#define APT 2                        // anchors per thread
#define APB (THREADS * APT)          // anchors per block = 512
#define BPI ((A_N + APB - 1) / APB)  // blocks per image = 391
#define NPART (B_N * BPI)

__device__ __forceinline__ float sl1(float d) {
    d = fabsf(d);
    return (d <= (1.0f / 9.0f)) ? (4.5f * d * d) : (d - (1.0f / 18.0f));
}

__global__ __launch_bounds__(THREADS, 6)
void focal_main(const float4* __restrict__ cls4,
                const float4* __restrict__ reg,
                const float4* __restrict__ anchors,
                const float* __restrict__ ann,
                float* __restrict__ pc, float* __restrict__ pr, float* __restrict__ pn)
{
    const int blk = blockIdx.x;
    const int b   = blockIdx.y;
    const int tid = threadIdx.x;

    __shared__ float4 sbox[M_N];
    __shared__ float  sarea[M_N];
    __shared__ float  wred[THREADS / 64][3];

    if (tid < M_N) {
        const float* p = ann + (size_t)(b * M_N + tid) * 5;
        float x1 = p[0], y1 = p[1], x2 = p[2], y2 = p[3];
        sbox[tid]  = make_float4(x1, y1, x2, y2);
        sarea[tid] = (x2 - x1) * (y2 - y1);
    }
    __syncthreads();

    const int abase = blk * APB + tid;

    float ax1[APT], ay1[APT], ax2[APT], ay2[APT], areaA[APT], pclsv[APT];
    float bi[APT], bS[APT];   // best inter / best S (= areaA + areaB of winning box)
    int   bj[APT];
    #pragma unroll
    for (int k = 0; k < APT; k++) {
        int a  = abase + k * THREADS;
        int al = (a < A_N) ? a : (A_N - 1);
        float4 v = anchors[al];
        ax1[k] = v.x; ay1[k] = v.y; ax2[k] = v.z; ay2[k] = v.w;
        areaA[k] = (v.z - v.x) * (v.w - v.y);
        bi[k] = -1.0f; bS[k] = 1.0f; bj[k] = 0;
        pclsv[k] = cls4[(size_t)b * A_N + al].x;   // coalesced float4, channel 0
    }

    #pragma unroll 8
    for (int j = 0; j < M_N; j++) {
        float4 bb = sbox[j];
        float  ab = sarea[j];
        #pragma unroll
        for (int k = 0; k < APT; k++) {
            float iw = fminf(ax2[k], bb.z) - fmaxf(ax1[k], bb.x);
            float ih = fminf(ay2[k], bb.w) - fmaxf(ay1[k], bb.y);
            iw = fmaxf(iw, 0.0f);
            ih = fmaxf(ih, 0.0f);
            float inter = iw * ih;
            float S = areaA[k] + ab;
            // iou_j > iou_best  <=>  inter_j*(S_b - i_b) > i_b*(S_j - inter_j)
            //                   <=>  inter_j*S_b > i_b*S_j   (cross terms cancel; ua>0 always)
            bool c = inter * bS[k] > bi[k] * S;
            bi[k] = c ? inter : bi[k];
            bS[k] = c ? S     : bS[k];
            bj[k] = c ? j     : bj[k];
        }
    }

    float cls_sum = 0.0f, reg_sum = 0.0f, npos = 0.0f;
    #pragma unroll
    for (int k = 0; k < APT; k++) {
        int a = abase + k * THREADS;
        if (a >= A_N) continue;
        // iou = bi/(bS-bi); ua >= 64 so no clamp. Division-free thresholds:
        // iou >= 0.5 <=> 3*bi >= bS ; iou < 0.4 <=> 7*bi < 2*bS
        bool pos = 3.0f * bi[k] >= bS[k];
        bool neg = 7.0f * bi[k] < 2.0f * bS[k];
        float p = fminf(fmaxf(pclsv[k], 1e-5f), 1.0f - 1e-5f);
        float q    = pos ? p : (1.0f - p);
        float coef = pos ? 0.25f : 0.75f;
        float omq  = 1.0f - q;
        float term = coef * omq * omq * (-__logf(q));
        cls_sum += (pos || neg) ? term : 0.0f;
        npos    += pos ? 1.0f : 0.0f;
        if (pos) {   // rare: exec-z skipped for most waves
            float4 bb = sbox[bj[k]];
            float aw = ax2[k] - ax1[k], ah = ay2[k] - ay1[k];
            float acx = ax1[k] + 0.5f * aw, acy = ay1[k] + 0.5f * ah;
            float gwr = bb.z - bb.x, ghr = bb.w - bb.y;
            float gcx = bb.x + 0.5f * gwr, gcy = bb.y + 0.5f * ghr;
            float gw = fmaxf(gwr, 1.0f), gh = fmaxf(ghr, 1.0f);
            float4 r = reg[(size_t)b * A_N + a];
            float rt0 = ((gcx - acx) / aw) / 0.1f;
            float rt1 = ((gcy - acy) / ah) / 0.1f;
            float rt2 = __logf(gw / aw) / 0.2f;
            float rt3 = __logf(gh / ah) / 0.2f;
            reg_sum += sl1(rt0 - r.x) + sl1(rt1 - r.y) + sl1(rt2 - r.z) + sl1(rt3 - r.w);
        }
    }

    // wave reduce (64 lanes)
    #pragma unroll
    for (int off = 32; off > 0; off >>= 1) {
        cls_sum += __shfl_down(cls_sum, off);
        reg_sum += __shfl_down(reg_sum, off);
        npos    += __shfl_down(npos, off);
    }
    int wid = tid >> 6;
    if ((tid & 63) == 0) {
        wred[wid][0] = cls_sum; wred[wid][1] = reg_sum; wred[wid][2] = npos;
    }
    __syncthreads();
    if (tid == 0) {
        float c = 0.0f, r = 0.0f, n = 0.0f;
        #pragma unroll
        for (int w = 0; w < THREADS / 64; w++) {
            c += wred[w][0]; r += wred[w][1]; n += wred[w][2];
        }
        int idx = b * BPI + blk;
        pc[idx] = c; pr[idx] = r; pn[idx] = n;   // SoA, every slot written each launch
    }
}

__global__ __launch_bounds__(512)
void focal_reduce(const float* __restrict__ pc, const float* __restrict__ pr,
                  const float* __restrict__ pn, float* __restrict__ out)
{
    __shared__ float scl[B_N], srg[B_N];
    int tid  = threadIdx.x;        // 512 threads = 8 waves, wave w handles image w
    int w    = tid >> 6;
    int lane = tid & 63;
    float cs = 0.0f, rs = 0.0f, np = 0.0f;
    for (int i = lane; i < BPI; i += 64) {     // coalesced SoA reads
        cs += pc[w * BPI + i];
        rs += pr[w * BPI + i];
        np += pn[w * BPI + i];
    }
    #pragma unroll
    for (int off = 32; off > 0; off >>= 1) {
        cs += __shfl_down(cs, off);
        rs += __shfl_down(rs, off);
        np += __shfl_down(np, off);
    }
    if (lane == 0) {
        scl[w] = cs / fmaxf(np, 1.0f);
        srg[w] = (np > 0.0f) ? rs / (4.0f * np) : 0.0f;
    }
    __syncthreads();
    if (tid == 0) {
        float c = 0.0f, r = 0.0f;
        #pragma unroll
        for (int i = 0; i < B_N; i++) { c += scl[i]; r += srg[i]; }
        out[0] = c / (float)B_N;
        out[1] = r / (float)B_N;
    }
}

extern "C" void kernel_launch(void* const* d_in, const int* in_sizes, int n_in,
                              void* d_out, int out_size, void* d_ws, size_t ws_size,
                              hipStream_t stream)
{
    const float4* cls4    = (const float4*)d_in[0];
    const float4* reg     = (const float4*)d_in[1];
    const float4* anchors = (const float4*)d_in[2];
    const float*  ann     = (const float*)d_in[3];
    float* pc = (float*)d_ws;              // [NPART]
    float* pr = pc + NPART;                // [NPART]
    float* pn = pr + NPART;                // [NPART]
    float* out = (float*)d_out;

    dim3 grid(BPI, B_N);
    focal_main<<<grid, THREADS, 0, stream>>>(cls4, reg, anchors, ann, pc, pr, pn);
    focal_reduce<<<1, 512, 0, stream>>>(pc, pr, pn, out);
}